// Round 6
// baseline (1660.516 us; speedup 1.0000x reference)
//
#include <hip/hip_runtime.h>
#include <hip/hip_bf16.h>
#include <cstdint>
#include <cstddef>

// Problem dims
#define SS   512
#define BB   64
#define EMBD 512
#define HIDD 512
#define MAXD 1024
#define NCLS 20
#define KCAT 1536
#define ROWS (SS*BB)   // 32768

// ---------- small helpers ----------
__device__ __forceinline__ uint16_t f2bf(float f) {
  uint32_t u = __float_as_uint(f);
  uint32_t r = u + 0x7fffu + ((u >> 16) & 1u);
  return (uint16_t)(r >> 16);
}
__device__ __forceinline__ float bf2f(uint32_t h) {
  return __uint_as_float(h << 16);
}
__device__ __forceinline__ uint32_t pk2(float a, float b) {
  return (uint32_t)f2bf(a) | ((uint32_t)f2bf(b) << 16);
}

#if defined(__has_builtin)
#if __has_builtin(__builtin_amdgcn_fdot2_f32_bf16)
#define USE_BF16_DOT2 1
#endif
#endif

#ifdef USE_BF16_DOT2
typedef __bf16 bf16x2_t __attribute__((ext_vector_type(2)));
__device__ __forceinline__ float dot2bf(uint32_t w, uint32_t c, float acc) {
  return __builtin_amdgcn_fdot2_f32_bf16(__builtin_bit_cast(bf16x2_t, w),
                                         __builtin_bit_cast(bf16x2_t, c), acc, false);
}
#else
__device__ __forceinline__ float dot2bf(uint32_t w, uint32_t c, float acc) {
  float w0 = __uint_as_float(w << 16);
  float w1 = __uint_as_float(w & 0xffff0000u);
  float c0 = __uint_as_float(c << 16);
  float c1 = __uint_as_float(c & 0xffff0000u);
  return fmaf(w1, c1, fmaf(w0, c0, acc));
}
#endif

__device__ __forceinline__ void gl_lds16(const void* g, void* l) {
  __builtin_amdgcn_global_load_lds((const __attribute__((address_space(1))) void*)g,
                                   (__attribute__((address_space(3))) void*)l,
                                   16, 0, 0);
}

typedef short v8s __attribute__((ext_vector_type(8)));
typedef float v4f __attribute__((ext_vector_type(4)));

// ---------- K0: gather emb -> cat[:,512:1024] (bf16), convert weights to bf16 ----------
__global__ __launch_bounds__(256) void prep_kernel(
    const int* __restrict__ inp, const float* __restrict__ table,
    const float* __restrict__ Wsl, const float* __restrict__ Wsr,
    const float* __restrict__ Wl,  const float* __restrict__ Wr,
    const float* __restrict__ Wmax,
    uint16_t* __restrict__ cat, uint16_t* __restrict__ wslb,
    uint16_t* __restrict__ wsrb, uint16_t* __restrict__ wlb,
    uint16_t* __restrict__ wrb, uint16_t* __restrict__ wmaxb)
{
  const int blk = blockIdx.x, t = threadIdx.x;
  if (blk < 8192) {
    const int r = blk * 4 + (t >> 6);
    const int lane = t & 63;
    const int token = inp[r];
    const float4* src = (const float4*)(table + (size_t)token * EMBD);
    uint16_t* dst = cat + (size_t)r * KCAT + 512;
#pragma unroll
    for (int p = 0; p < 2; ++p) {
      const int slot = lane + 64 * p;   // 0..127 float4 slots per row
      float4 v = src[slot];
      uint2 o;
      o.x = pk2(v.x, v.y);
      o.y = pk2(v.z, v.w);
      *(uint2*)(dst + slot * 4) = o;
    }
  } else {
    size_t flat = (size_t)(blk - 8192) * 2048 + (size_t)t * 8;
    const float* src; uint16_t* dst; size_t off;
    if (flat < 262144)       { src = Wsl;  dst = wslb;  off = flat; }
    else if (flat < 524288)  { src = Wsr;  dst = wsrb;  off = flat - 262144; }
    else if (flat < 786432)  { src = Wl;   dst = wlb;   off = flat - 524288; }
    else if (flat < 1048576) { src = Wr;   dst = wrb;   off = flat - 786432; }
    else                     { src = Wmax; dst = wmaxb; off = flat - 1048576; }
    float4 v0 = *(const float4*)(src + off);
    float4 v1 = *(const float4*)(src + off + 4);
    uint4 o;
    o.x = pk2(v0.x, v0.y); o.y = pk2(v0.z, v0.w);
    o.z = pk2(v1.x, v1.y); o.w = pk2(v1.z, v1.w);
    *(uint4*)(dst + off) = o;
  }
}

// ---------- GEMM (m97-style): C[M x 1024] = A[M x K] @ W^T, 128x128 tiles, BK=64 ----------
// MODE 0: out = A@W^T + bias -> bf16 store (proj GEMM, W split at n=512)
// MODE 1: v = tanh(A@W^T + bias); partial[mb][b][n] = max over the block's 2 s-rows
template<int MODE>
__global__ __launch_bounds__(256, 2) void gemm_kernel(
    const uint16_t* __restrict__ A, int lda, int K,
    const uint16_t* __restrict__ W0, const uint16_t* __restrict__ W1,
    const float* __restrict__ bias0, const float* __restrict__ bias1,
    uint16_t* __restrict__ outb, float* __restrict__ partial)
{
  __shared__ unsigned char smem[32768];
  uint16_t* lA = (uint16_t*)smem;            // 128x64 bf16 = 16 KB
  uint16_t* lW = (uint16_t*)(smem + 16384);  // 128x64 bf16 = 16 KB

  const int tid = threadIdx.x;
  const int mb = blockIdx.x, nb = blockIdx.y;
  const int m0 = mb * 128, n0 = nb * 128;

  const uint16_t* Wp = W0;
  const float* biasp = bias0;
  int nr0 = n0;
  if (MODE == 0 && n0 >= 512) { Wp = W1; biasp = bias1; nr0 = n0 - 512; }

  const int w = tid >> 6, lane = tid & 63;
  const int mw = w & 1, nw = w >> 1;

  v4f acc[4][4];
#pragma unroll
  for (int i = 0; i < 4; ++i)
#pragma unroll
    for (int j = 0; j < 4; ++j) {
      v4f z = {0.f, 0.f, 0.f, 0.f};
      acc[i][j] = z;
    }

  const int r_st = tid >> 3;   // + p*32
  const int u_st = tid & 7;

  for (int kk = 0; kk < K; kk += 64) {
    __syncthreads();
#pragma unroll
    for (int p = 0; p < 4; ++p) {
      const int r = p * 32 + r_st;
      gl_lds16(A + (size_t)(m0 + r) * lda + kk + u_st * 8, lA + (p * 256 + tid) * 8);
    }
#pragma unroll
    for (int p = 0; p < 4; ++p) {
      const int r = p * 32 + r_st;
      gl_lds16(Wp + (size_t)(nr0 + r) * K + kk + u_st * 8, lW + (p * 256 + tid) * 8);
    }
    __syncthreads();
#pragma unroll
    for (int ks = 0; ks < 2; ++ks) {
      v8s af[4], wf[4];
#pragma unroll
      for (int i = 0; i < 4; ++i)
        af[i] = *(const v8s*)&lA[(mw * 64 + i * 16 + (lane & 15)) * 64 + ks * 32 + (lane >> 4) * 8];
#pragma unroll
      for (int j = 0; j < 4; ++j)
        wf[j] = *(const v8s*)&lW[(nw * 64 + j * 16 + (lane & 15)) * 64 + ks * 32 + (lane >> 4) * 8];
#pragma unroll
      for (int i = 0; i < 4; ++i)
#pragma unroll
        for (int j = 0; j < 4; ++j)
          acc[i][j] = __builtin_amdgcn_mfma_f32_16x16x32_bf16(af[i], wf[j], acc[i][j], 0, 0, 0);
    }
  }

  __syncthreads();  // all LDS frag reads done before epilogue reuse

  if (MODE == 0) {
#pragma unroll
    for (int i = 0; i < 4; ++i)
#pragma unroll
      for (int j = 0; j < 4; ++j) {
        const int nl = nw * 64 + j * 16 + (lane & 15);
        const float bv = biasp[nr0 + nl];
        const int colg = n0 + nl;
#pragma unroll
        for (int r = 0; r < 4; ++r) {
          const int rowg = m0 + mw * 64 + i * 16 + (lane >> 4) * 4 + r;
          outb[(size_t)rowg * 1024 + colg] = f2bf(acc[i][j][r] + bv);
        }
      }
  } else {
    float* lred = (float*)smem;   // 64 b x 128 n f32 = 32 KB
    if (mw == 1) {
#pragma unroll
      for (int i = 0; i < 4; ++i)
#pragma unroll
        for (int j = 0; j < 4; ++j) {
          const int nl = nw * 64 + j * 16 + (lane & 15);
          const float bv = biasp[nr0 + nl];
#pragma unroll
          for (int r = 0; r < 4; ++r) {
            const int bl = i * 16 + (lane >> 4) * 4 + r;
            lred[bl * 128 + nl] = tanhf(acc[i][j][r] + bv);
          }
        }
    }
    __syncthreads();
    if (mw == 0) {
#pragma unroll
      for (int i = 0; i < 4; ++i)
#pragma unroll
        for (int j = 0; j < 4; ++j) {
          const int nl = nw * 64 + j * 16 + (lane & 15);
          const float bv = biasp[nr0 + nl];
#pragma unroll
          for (int r = 0; r < 4; ++r) {
            const int bl = i * 16 + (lane >> 4) * 4 + r;
            const float v = tanhf(acc[i][j][r] + bv);
            partial[((size_t)mb * 64 + bl) * 1024 + n0 + nl] = fmaxf(v, lred[bl * 128 + nl]);
          }
        }
    }
  }
}

// ---------- K2: bidirectional recurrence, W-in-LDS, c-amortized dot ----------
// 256 blocks x 512 threads: block = (batch-pair pb, dir d, h-quarter qh).
// Thread = (hp 0..31 -> 4 rows, kwi 0..15 -> 32-k window): per step 16 W b128 +
// 4+4 c/d b128 (vs round-5's 16+32: c re-reads were 2/3 of LDS traffic; the LDS
// pipe moves 1KB/wave-op even for broadcast reads). Partials via part[row][kwi][b2]
// float2; finalize = one row per lane + shfl_xor(1) to pack bf16 h-pairs.
// Exchange: round-5-validated relaxed u64 {seq|payload} agent atomics, parity dbuf.
__global__ __launch_bounds__(512) void scan_kernel(
    const uint16_t* __restrict__ ee,     // [32768][1024] bf16: ls | rs
    const uint16_t* __restrict__ wlb, const uint16_t* __restrict__ wrb,
    const float* __restrict__ bl, const float* __restrict__ br,
    const float* __restrict__ cl0, const float* __restrict__ cr0,
    uint16_t* __restrict__ cat,
    uint64_t* __restrict__ cbuf)
{
  const int tid = threadIdx.x;
  const int bid = blockIdx.x;
  const int qh = bid >> 6;          // h-quarter 0..3 (partners differ by 64 -> same XCD slot)
  const int pb = (bid >> 1) & 31;   // batch pair
  const int d  = bid & 1;
  const int b0 = pb * 2;

  const int hp  = tid >> 4;         // 0..31: row group of 4
  const int kwi = tid & 15;         // 0..15: 32-element k-window

  __shared__ uint32_t wlds[128 * 260];   // 133120 B, j-permuted rows (stride 260 u32)
  __shared__ uint32_t cpair[2 * 256];    // c per batch as 256 bf16-pairs
  __shared__ float    part[128 * 36];    // [row][kwi][b2] float2, row stride 36 u32

  // ---- stage W quarter into LDS: each thread stages exactly its read-set ----
  {
    const uint16_t* wbase = (d ? wrb : wlb) + (size_t)(qh * 128) * HIDD;
#pragma unroll
    for (int rr = 0; rr < 4; ++rr) {
      const uint16_t* wrow = wbase + (size_t)(4 * hp + rr) * HIDD + kwi * 32;
      uint32_t* dst = &wlds[(4 * hp + rr) * 260 + kwi * 4];
#pragma unroll
      for (int j = 0; j < 4; ++j) {
        uint4 q = ((const uint4*)wrow)[j];
        *(uint4*)(dst + j * 64) = q;
      }
    }
  }
  // init c for both batches (same init vector)
  {
    const int b2 = tid >> 8, idx = tid & 255;
    const float* c0v = d ? cr0 : cl0;
    float2 cv = ((const float2*)c0v)[idx];
    cpair[b2 * 256 + idx] = pk2(cv.x, cv.y);
  }
  // finalize geometry: lane fr (=tid<128) owns row fr of the quarter, both batches
  const int fr = tid;               // valid when tid < 128
  const int fb2 = fr & 1;           // publish slot batch after shfl pack
  const int fp  = fr >> 1;          // pair index
  float biasf = 0.f;
  if (tid < 128) biasf = (d ? br : bl)[qh * 128 + fr];
  __syncthreads();

  const size_t ecolh = (size_t)(d * 512 + qh * 128 + fr);   // single h column
  const int fcol = (d ? 1024 : 0) + qh * 128 + 2 * fp;      // cat col for packed pair

  // gather-lane geometry (tid >= 128): partner pi 0..2, word j 0..127
  const int g  = tid - 128;
  const int pi = g >> 7;
  const int gj = g & 127;
  const int pq = (qh + 1 + pi) & 3;
  const int pbid = (pq << 6) | (pb << 1) | d;

  // 2-deep e prefetch ring: per lane 2 scalar bf16 (batch b0 and b0+1, same h)
  uint16_t e0a = 0, e0b = 0, e1a = 0, e1b = 0;
  if (tid < 128) {
    const int s0i = d ? 511 : 0;
    const int s1i = d ? 510 : 1;
    e0a = ee[(size_t)(s0i * BB + b0) * 1024 + ecolh];
    e0b = ee[(size_t)(s0i * BB + b0 + 1) * 1024 + ecolh];
    e1a = ee[(size_t)(s1i * BB + b0) * 1024 + ecolh];
    e1b = ee[(size_t)(s1i * BB + b0 + 1) * 1024 + ecolh];
  }

  uint32_t prPrev = 0;
  int sPrev = -1;

  for (int i = 0; i < 512; ++i) {
    const int s = d ? (511 - i) : i;
    uint16_t e2a = 0, e2b = 0;
    if (tid < 128) {
      const int i2 = (i + 2) & 511;
      const int s2 = d ? (511 - i2) : i2;
      e2a = ee[(size_t)(s2 * BB + b0) * 1024 + ecolh];
      e2b = ee[(size_t)(s2 * BB + b0 + 1) * 1024 + ecolh];
      // pipelined cat store from previous iteration (drains during the dot)
      if (sPrev >= 0)
        *(uint32_t*)&cat[(size_t)(sPrev * BB + b0 + fb2) * KCAT + fcol] = prPrev;
    }

    // dot: rows 4hp..4hp+3, k-window [kwi*32,+32), both batches
    {
      const uint32_t* cb0 = &cpair[kwi * 16];
      const uint32_t* cb1 = &cpair[256 + kwi * 16];
      const uint32_t* wb  = &wlds[(4 * hp) * 260 + kwi * 4];
      float a0[4] = {0.f, 0.f, 0.f, 0.f};
      float a1[4] = {0.f, 0.f, 0.f, 0.f};
#pragma unroll
      for (int j = 0; j < 4; ++j) {
        uint4 c4 = *(const uint4*)(cb0 + j * 4);
        uint4 d4 = *(const uint4*)(cb1 + j * 4);
#pragma unroll
        for (int rr = 0; rr < 4; ++rr) {
          uint4 w4 = *(const uint4*)(wb + rr * 260 + j * 64);
          a0[rr] = dot2bf(w4.x, c4.x, a0[rr]);
          a0[rr] = dot2bf(w4.y, c4.y, a0[rr]);
          a0[rr] = dot2bf(w4.z, c4.z, a0[rr]);
          a0[rr] = dot2bf(w4.w, c4.w, a0[rr]);
          a1[rr] = dot2bf(w4.x, d4.x, a1[rr]);
          a1[rr] = dot2bf(w4.y, d4.y, a1[rr]);
          a1[rr] = dot2bf(w4.z, d4.z, a1[rr]);
          a1[rr] = dot2bf(w4.w, d4.w, a1[rr]);
        }
      }
#pragma unroll
      for (int rr = 0; rr < 4; ++rr) {
        float2 pv = {a0[rr], a1[rr]};
        *(float2*)&part[(4 * hp + rr) * 36 + kwi * 2] = pv;
      }
    }
    __syncthreads();

    if (tid < 128) {
      // finalize row fr: sum 16 kwi partials for both batches (float4 = 2 kwi x 2 b)
      const float* p = &part[fr * 36];
      float s0 = 0.f, s1 = 0.f;
#pragma unroll
      for (int t = 0; t < 8; ++t) {
        float4 q = *(const float4*)(p + 4 * t);
        s0 += q.x + q.z;
        s1 += q.y + q.w;
      }
      float t0 = tanhf(s0 + biasf + bf2f(e0a));   // batch b0, row fr
      float t1 = tanhf(s1 + biasf + bf2f(e0b));   // batch b0+1, row fr
      // pack h-pairs across adjacent lanes
      float u0 = __shfl_xor(t0, 1);
      float u1 = __shfl_xor(t1, 1);
      uint32_t pr = (fr & 1) ? pk2(u1, t1) : pk2(t0, u0);  // even: b0 pair; odd: b1 pair
      cpair[fb2 * 256 + qh * 64 + fp] = pr;
      if (i != 511) {
        const int slot = fb2 * 64 + fp;   // keep round-5 slot layout (b2 = slot>>6)
        uint64_t pkt = ((uint64_t)(uint32_t)(i + 1) << 32) | (uint64_t)pr;
        __hip_atomic_store(&cbuf[(size_t)(((i & 1) * 256 + bid) * 128 + slot)],
                           pkt, __ATOMIC_RELAXED, __HIP_MEMORY_SCOPE_AGENT);
        prPrev = pr; sPrev = s;
      } else {
        *(uint32_t*)&cat[(size_t)(s * BB + b0 + fb2) * KCAT + fcol] = pr;
      }
    } else if (i != 511) {
      // poll-gather one partner word; seq embedded -> single round trip
      const uint64_t want = (uint64_t)(uint32_t)(i + 1);
      const uint64_t* slot = &cbuf[(size_t)(((i & 1) * 256 + pbid) * 128 + gj)];
      uint64_t v = __hip_atomic_load(slot, __ATOMIC_RELAXED, __HIP_MEMORY_SCOPE_AGENT);
      while ((v >> 32) != want) {
        __builtin_amdgcn_s_sleep(1);
        v = __hip_atomic_load(slot, __ATOMIC_RELAXED, __HIP_MEMORY_SCOPE_AGENT);
      }
      cpair[(gj >> 6) * 256 + pq * 64 + (gj & 63)] = (uint32_t)v;
    }

    if (i == 511) break;
    __syncthreads();

    e0a = e1a; e0b = e1b; e1a = e2a; e1b = e2b;
  }
}

// ---------- K4: max-reduce partials, classifier, log_softmax ----------
__global__ __launch_bounds__(256) void final_kernel(
    const float* __restrict__ partial, const float* __restrict__ Wdoc,
    const float* __restrict__ bdoc, float* __restrict__ out)
{
  const int b = blockIdx.x, t = threadIdx.x;
  __shared__ float ym[1024];
  __shared__ float lg[32];
  float m0 = -2.f, m1 = -2.f, m2 = -2.f, m3 = -2.f;
  for (int mg = 0; mg < 256; ++mg) {
    const float* p = partial + ((size_t)mg * 64 + b) * 1024;
    m0 = fmaxf(m0, p[t]);
    m1 = fmaxf(m1, p[t + 256]);
    m2 = fmaxf(m2, p[t + 512]);
    m3 = fmaxf(m3, p[t + 768]);
  }
  ym[t] = m0; ym[t + 256] = m1; ym[t + 512] = m2; ym[t + 768] = m3;
  __syncthreads();
  if (t < NCLS) {
    const float* wr = Wdoc + (size_t)t * 1024;
    float a0 = 0.f, a1 = 0.f, a2 = 0.f, a3 = 0.f;
    for (int n = 0; n < 1024; n += 4) {
      a0 = fmaf(ym[n], wr[n], a0);
      a1 = fmaf(ym[n + 1], wr[n + 1], a1);
      a2 = fmaf(ym[n + 2], wr[n + 2], a2);
      a3 = fmaf(ym[n + 3], wr[n + 3], a3);
    }
    lg[t] = (a0 + a1) + (a2 + a3) + bdoc[t];
  }
  __syncthreads();
  if (t < NCLS) {
    float mx = -1e30f;
    for (int c = 0; c < NCLS; ++c) mx = fmaxf(mx, lg[c]);
    float ssum = 0.f;
    for (int c = 0; c < NCLS; ++c) ssum += expf(lg[c] - mx);
    out[b * NCLS + t] = lg[t] - mx - logf(ssum);
  }
}

// ---------- launch ----------
extern "C" void kernel_launch(void* const* d_in, const int* in_sizes, int n_in,
                              void* d_out, int out_size, void* d_ws, size_t ws_size,
                              hipStream_t stream) {
  const int*   inp   = (const int*)  d_in[0];
  const float* table = (const float*)d_in[1];
  const float* cl0   = (const float*)d_in[2];
  const float* cr0   = (const float*)d_in[3];
  const float* Wl    = (const float*)d_in[4];
  const float* bl    = (const float*)d_in[5];
  const float* Wr    = (const float*)d_in[6];
  const float* br    = (const float*)d_in[7];
  const float* Wsl   = (const float*)d_in[8];
  const float* bsl   = (const float*)d_in[9];
  const float* Wsr   = (const float*)d_in[10];
  const float* bsr   = (const float*)d_in[11];
  const float* Wmax  = (const float*)d_in[12];
  const float* bmax  = (const float*)d_in[13];
  const float* Wdoc  = (const float*)d_in[14];
  const float* bdoc  = (const float*)d_in[15];

  uint8_t* ws = (uint8_t*)d_ws;
  uint16_t* cat     = (uint16_t*)(ws);                 // 32768*1536*2 = 100663296
  uint16_t* ee      = (uint16_t*)(ws + 100663296);     // 32768*1024*2 = 67108864
  float*    partial = (float*)   (ws + 167772160);     // 256*64*1024*4 = 67108864
  uint16_t* wslb    = (uint16_t*)(ws + 234881024);     // 524288
  uint16_t* wsrb    = (uint16_t*)(ws + 235405312);     // 524288
  uint16_t* wmaxb   = (uint16_t*)(ws + 235929600);     // 3145728
  uint16_t* wlb     = (uint16_t*)(ws + 239075328);     // 524288
  uint16_t* wrb     = (uint16_t*)(ws + 239599616);     // 524288
  // cbuf (u64 seq|payload, 2 parity x 256 bid x 128 words = 512 KB) overlays the
  // START of `partial`: poisoned 0xAA at launch (seq never matches), and gemm<1>
  // fully overwrites partial AFTER the scan completes. No ws growth.
  uint64_t* cbuf    = (uint64_t*)(ws + 167772160);

  prep_kernel<<<9472, 256, 0, stream>>>(inp, table, Wsl, Wsr, Wl, Wr, Wmax,
                                        cat, wslb, wsrb, wlb, wrb, wmaxb);
  gemm_kernel<0><<<dim3(256, 8), 256, 0, stream>>>(cat + 512, KCAT, 512, wslb, wsrb,
                                                   bsl, bsr, ee, nullptr);
  scan_kernel<<<256, 512, 0, stream>>>(ee, wlb, wrb, bl, br, cl0, cr0, cat, cbuf);
  gemm_kernel<1><<<dim3(256, 8), 256, 0, stream>>>(cat, KCAT, KCAT, wmaxb, nullptr,
                                                   bmax, nullptr, nullptr, partial);
  final_kernel<<<64, 256, 0, stream>>>(partial, Wdoc, bdoc, (float*)d_out);
}

// Round 7
// 1481.194 us; speedup vs baseline: 1.1211x; 1.1211x over previous
//
#include <hip/hip_runtime.h>
#include <hip/hip_bf16.h>
#include <cstdint>
#include <cstddef>

// Problem dims
#define SS   512
#define BB   64
#define EMBD 512
#define HIDD 512
#define MAXD 1024
#define NCLS 20
#define KCAT 1536
#define ROWS (SS*BB)   // 32768

// ---------- small helpers ----------
__device__ __forceinline__ uint16_t f2bf(float f) {
  uint32_t u = __float_as_uint(f);
  uint32_t r = u + 0x7fffu + ((u >> 16) & 1u);
  return (uint16_t)(r >> 16);
}
__device__ __forceinline__ float bf2f(uint32_t h) {
  return __uint_as_float(h << 16);
}
__device__ __forceinline__ uint32_t pk2(float a, float b) {
  return (uint32_t)f2bf(a) | ((uint32_t)f2bf(b) << 16);
}

#if defined(__has_builtin)
#if __has_builtin(__builtin_amdgcn_fdot2_f32_bf16)
#define USE_BF16_DOT2 1
#endif
#endif

#ifdef USE_BF16_DOT2
typedef __bf16 bf16x2_t __attribute__((ext_vector_type(2)));
__device__ __forceinline__ float dot2bf(uint32_t w, uint32_t c, float acc) {
  return __builtin_amdgcn_fdot2_f32_bf16(__builtin_bit_cast(bf16x2_t, w),
                                         __builtin_bit_cast(bf16x2_t, c), acc, false);
}
#else
__device__ __forceinline__ float dot2bf(uint32_t w, uint32_t c, float acc) {
  float w0 = __uint_as_float(w << 16);
  float w1 = __uint_as_float(w & 0xffff0000u);
  float c0 = __uint_as_float(c << 16);
  float c1 = __uint_as_float(c & 0xffff0000u);
  return fmaf(w1, c1, fmaf(w0, c0, acc));
}
#endif

__device__ __forceinline__ void gl_lds16(const void* g, void* l) {
  __builtin_amdgcn_global_load_lds((const __attribute__((address_space(1))) void*)g,
                                   (__attribute__((address_space(3))) void*)l,
                                   16, 0, 0);
}

typedef short v8s __attribute__((ext_vector_type(8)));
typedef float v4f __attribute__((ext_vector_type(4)));

// ---------- K0: gather emb -> cat[:,512:1024] (bf16), convert weights to bf16 ----------
__global__ __launch_bounds__(256) void prep_kernel(
    const int* __restrict__ inp, const float* __restrict__ table,
    const float* __restrict__ Wsl, const float* __restrict__ Wsr,
    const float* __restrict__ Wl,  const float* __restrict__ Wr,
    const float* __restrict__ Wmax,
    uint16_t* __restrict__ cat, uint16_t* __restrict__ wslb,
    uint16_t* __restrict__ wsrb, uint16_t* __restrict__ wlb,
    uint16_t* __restrict__ wrb, uint16_t* __restrict__ wmaxb)
{
  const int blk = blockIdx.x, t = threadIdx.x;
  if (blk < 8192) {
    const int r = blk * 4 + (t >> 6);
    const int lane = t & 63;
    const int token = inp[r];
    const float4* src = (const float4*)(table + (size_t)token * EMBD);
    uint16_t* dst = cat + (size_t)r * KCAT + 512;
#pragma unroll
    for (int p = 0; p < 2; ++p) {
      const int slot = lane + 64 * p;   // 0..127 float4 slots per row
      float4 v = src[slot];
      uint2 o;
      o.x = pk2(v.x, v.y);
      o.y = pk2(v.z, v.w);
      *(uint2*)(dst + slot * 4) = o;
    }
  } else {
    size_t flat = (size_t)(blk - 8192) * 2048 + (size_t)t * 8;
    const float* src; uint16_t* dst; size_t off;
    if (flat < 262144)       { src = Wsl;  dst = wslb;  off = flat; }
    else if (flat < 524288)  { src = Wsr;  dst = wsrb;  off = flat - 262144; }
    else if (flat < 786432)  { src = Wl;   dst = wlb;   off = flat - 524288; }
    else if (flat < 1048576) { src = Wr;   dst = wrb;   off = flat - 786432; }
    else                     { src = Wmax; dst = wmaxb; off = flat - 1048576; }
    float4 v0 = *(const float4*)(src + off);
    float4 v1 = *(const float4*)(src + off + 4);
    uint4 o;
    o.x = pk2(v0.x, v0.y); o.y = pk2(v0.z, v0.w);
    o.z = pk2(v1.x, v1.y); o.w = pk2(v1.z, v1.w);
    *(uint4*)(dst + off) = o;
  }
}

// ---------- GEMM (m97-style): C[M x 1024] = A[M x K] @ W^T, 128x128 tiles, BK=64 ----------
// MODE 0: out = A@W^T + bias -> bf16 store (proj GEMM, W split at n=512)
// MODE 1: v = tanh(A@W^T + bias); partial[mb][b][n] = max over the block's 2 s-rows
template<int MODE>
__global__ __launch_bounds__(256, 2) void gemm_kernel(
    const uint16_t* __restrict__ A, int lda, int K,
    const uint16_t* __restrict__ W0, const uint16_t* __restrict__ W1,
    const float* __restrict__ bias0, const float* __restrict__ bias1,
    uint16_t* __restrict__ outb, float* __restrict__ partial)
{
  __shared__ unsigned char smem[32768];
  uint16_t* lA = (uint16_t*)smem;            // 128x64 bf16 = 16 KB
  uint16_t* lW = (uint16_t*)(smem + 16384);  // 128x64 bf16 = 16 KB

  const int tid = threadIdx.x;
  const int mb = blockIdx.x, nb = blockIdx.y;
  const int m0 = mb * 128, n0 = nb * 128;

  const uint16_t* Wp = W0;
  const float* biasp = bias0;
  int nr0 = n0;
  if (MODE == 0 && n0 >= 512) { Wp = W1; biasp = bias1; nr0 = n0 - 512; }

  const int w = tid >> 6, lane = tid & 63;
  const int mw = w & 1, nw = w >> 1;

  v4f acc[4][4];
#pragma unroll
  for (int i = 0; i < 4; ++i)
#pragma unroll
    for (int j = 0; j < 4; ++j) {
      v4f z = {0.f, 0.f, 0.f, 0.f};
      acc[i][j] = z;
    }

  const int r_st = tid >> 3;   // + p*32
  const int u_st = tid & 7;

  for (int kk = 0; kk < K; kk += 64) {
    __syncthreads();
#pragma unroll
    for (int p = 0; p < 4; ++p) {
      const int r = p * 32 + r_st;
      gl_lds16(A + (size_t)(m0 + r) * lda + kk + u_st * 8, lA + (p * 256 + tid) * 8);
    }
#pragma unroll
    for (int p = 0; p < 4; ++p) {
      const int r = p * 32 + r_st;
      gl_lds16(Wp + (size_t)(nr0 + r) * K + kk + u_st * 8, lW + (p * 256 + tid) * 8);
    }
    __syncthreads();
#pragma unroll
    for (int ks = 0; ks < 2; ++ks) {
      v8s af[4], wf[4];
#pragma unroll
      for (int i = 0; i < 4; ++i)
        af[i] = *(const v8s*)&lA[(mw * 64 + i * 16 + (lane & 15)) * 64 + ks * 32 + (lane >> 4) * 8];
#pragma unroll
      for (int j = 0; j < 4; ++j)
        wf[j] = *(const v8s*)&lW[(nw * 64 + j * 16 + (lane & 15)) * 64 + ks * 32 + (lane >> 4) * 8];
#pragma unroll
      for (int i = 0; i < 4; ++i)
#pragma unroll
        for (int j = 0; j < 4; ++j)
          acc[i][j] = __builtin_amdgcn_mfma_f32_16x16x32_bf16(af[i], wf[j], acc[i][j], 0, 0, 0);
    }
  }

  __syncthreads();  // all LDS frag reads done before epilogue reuse

  if (MODE == 0) {
#pragma unroll
    for (int i = 0; i < 4; ++i)
#pragma unroll
      for (int j = 0; j < 4; ++j) {
        const int nl = nw * 64 + j * 16 + (lane & 15);
        const float bv = biasp[nr0 + nl];
        const int colg = n0 + nl;
#pragma unroll
        for (int r = 0; r < 4; ++r) {
          const int rowg = m0 + mw * 64 + i * 16 + (lane >> 4) * 4 + r;
          outb[(size_t)rowg * 1024 + colg] = f2bf(acc[i][j][r] + bv);
        }
      }
  } else {
    float* lred = (float*)smem;   // 64 b x 128 n f32 = 32 KB
    if (mw == 1) {
#pragma unroll
      for (int i = 0; i < 4; ++i)
#pragma unroll
        for (int j = 0; j < 4; ++j) {
          const int nl = nw * 64 + j * 16 + (lane & 15);
          const float bv = biasp[nr0 + nl];
#pragma unroll
          for (int r = 0; r < 4; ++r) {
            const int bl = i * 16 + (lane >> 4) * 4 + r;
            lred[bl * 128 + nl] = tanhf(acc[i][j][r] + bv);
          }
        }
    }
    __syncthreads();
    if (mw == 0) {
#pragma unroll
      for (int i = 0; i < 4; ++i)
#pragma unroll
        for (int j = 0; j < 4; ++j) {
          const int nl = nw * 64 + j * 16 + (lane & 15);
          const float bv = biasp[nr0 + nl];
#pragma unroll
          for (int r = 0; r < 4; ++r) {
            const int bl = i * 16 + (lane >> 4) * 4 + r;
            const float v = tanhf(acc[i][j][r] + bv);
            partial[((size_t)mb * 64 + bl) * 1024 + n0 + nl] = fmaxf(v, lred[bl * 128 + nl]);
          }
        }
    }
  }
}

// ---------- K2: bidirectional recurrence, W-in-LDS, conflict-free c-amortized dot ----------
// 256 blocks x 512 threads: block = (batch-pair pb, dir d, h-quarter qh).
// Thread = (rgrp 0..31 -> 4 rows, kwi 0..15 -> 32-elem k-window), kwi in LOW lane
// bits. Layouts (R6 lesson: lane-stride must be 4 u32 = 16 B, or broadcast):
//   W:  [row][j 0..3][kwi 0..15][4 u32], row stride 260 -> dot reads lane-stride 4.
//   cT: [b][j][kwi][4 u32] (stride 264)  -> lane-stride 4, 4-lane rgrp broadcast.
//   part: [row][b][16 kwi] f32, row stride 34, b stride 16 -> 16B-aligned float4
//         finalize reads at lane-stride 4; scalar writes <=2-way.
// Per-step LDS ~227 KB vs R5's 390 KB (c re-reads were 2/3 of traffic).
// Exchange/finalize/publish/poll identical to round 5 (1098 us validated):
// relaxed u64 {seq|payload} agent atomics, parity dbuf, pipelined cat stores.
__global__ __launch_bounds__(512) void scan_kernel(
    const uint16_t* __restrict__ ee,     // [32768][1024] bf16: ls | rs
    const uint16_t* __restrict__ wlb, const uint16_t* __restrict__ wrb,
    const float* __restrict__ bl, const float* __restrict__ br,
    const float* __restrict__ cl0, const float* __restrict__ cr0,
    uint16_t* __restrict__ cat,
    uint64_t* __restrict__ cbuf)
{
  const int tid = threadIdx.x;
  const int bid = blockIdx.x;
  const int qh = bid >> 6;          // h-quarter 0..3
  const int pb = (bid >> 1) & 31;   // batch pair
  const int d  = bid & 1;
  const int b0 = pb * 2;

  const int rgrp = tid >> 4;        // 0..31: 4-row group
  const int kwi  = tid & 15;        // 0..15: 32-elem (16 u32) k-window

  __shared__ uint32_t wlds[128 * 260];   // 133120 B, [row][j][kwi][4]
  __shared__ uint32_t cT[2 * 264];       // 2112 B,  [b][j][kwi][4]
  __shared__ float    part[128 * 34];    // 17408 B, [row][b:16][kwi]

  // ---- stage W quarter into LDS (j-transposed row layout) ----
  {
    const uint16_t* wbase = (d ? wrb : wlb) + (size_t)(qh * 128) * HIDD;
#pragma unroll
    for (int rr = 0; rr < 4; ++rr) {
      const int row = 4 * rgrp + rr;
      const uint16_t* src = wbase + (size_t)row * HIDD;
#pragma unroll
      for (int j = 0; j < 4; ++j) {
        uint4 v = *(const uint4*)(src + (kwi * 16 + j * 4) * 2);
        *(uint4*)&wlds[row * 260 + j * 64 + kwi * 4] = v;
      }
    }
  }
  // init cT from c0 (both batches, same init vector), transposed positions
  if (tid < 512) {
    const int b2 = tid >> 8, m = tid & 255;   // m = u32 index within c
    const float* c0v = d ? cr0 : cl0;
    float2 cv = ((const float2*)c0v)[m];
    cT[b2 * 264 + ((m >> 2) & 3) * 64 + (m >> 4) * 4 + (m & 3)] = pk2(cv.x, cv.y);
  }
  // finalize geometry (round-5 identical): tid<128: fb2 = tid>>6 batch, fp = tid&63 pair
  const int fb2 = tid >> 6;
  const int fp  = tid & 63;
  float2 biasv = {0.f, 0.f};
  if (tid < 128) {
    const float* bvec = d ? br : bl;
    biasv = ((const float2*)bvec)[qh * 64 + fp];
  }
  __syncthreads();

  const size_t ecol = (size_t)(d * 512 + qh * 128 + 2 * fp);
  const int fcol = (d ? 1024 : 0) + qh * 128 + 2 * fp;

  // gather-lane geometry (tid >= 128): partner pi 0..2, word gj 0..127
  const int g  = tid - 128;
  const int pi = g >> 7;
  const int gj = g & 127;
  const int pq = (qh + 1 + pi) & 3;
  const int pbid = (pq << 6) | (pb << 1) | d;
  // destination in cT for gathered word: batch gj>>6, u32 index m = pq*64 + (gj&63)
  const int gm = pq * 64 + (gj & 63);
  const int gdst = (gj >> 6) * 264 + ((gm >> 2) & 3) * 64 + (gm >> 4) * 4 + (gm & 3);

  // 2-deep ee prefetch ring
  uint32_t ep0 = 0, ep1 = 0;
  if (tid < 128) {
    const int s0i = d ? 511 : 0;
    const int s1i = d ? 510 : 1;
    ep0 = *(const uint32_t*)&ee[(size_t)(s0i * BB + b0 + fb2) * 1024 + ecol];
    ep1 = *(const uint32_t*)&ee[(size_t)(s1i * BB + b0 + fb2) * 1024 + ecol];
  }

  uint32_t prPrev = 0;
  int sPrev = -1;

  for (int i = 0; i < 512; ++i) {
    const int s = d ? (511 - i) : i;
    uint32_t ep2 = 0;
    if (tid < 128) {
      const int i2 = (i + 2) & 511;
      const int s2 = d ? (511 - i2) : i2;
      ep2 = *(const uint32_t*)&ee[(size_t)(s2 * BB + b0 + fb2) * 1024 + ecol];
      // pipelined cat store from previous iteration (drains during the dot)
      if (sPrev >= 0)
        *(uint32_t*)&cat[(size_t)(sPrev * BB + b0 + fb2) * KCAT + fcol] = prPrev;
    }

    // dot: rows 4rgrp..+3, k-window kwi, both batches. All reads lane-stride-4.
    {
      const uint32_t* wb  = &wlds[(4 * rgrp) * 260 + kwi * 4];
      const uint32_t* c0p = &cT[kwi * 4];
      const uint32_t* c1p = &cT[264 + kwi * 4];
      float a0[4] = {0.f, 0.f, 0.f, 0.f};
      float a1[4] = {0.f, 0.f, 0.f, 0.f};
#pragma unroll
      for (int j = 0; j < 4; ++j) {
        uint4 c4 = *(const uint4*)(c0p + j * 64);
        uint4 d4 = *(const uint4*)(c1p + j * 64);
#pragma unroll
        for (int rr = 0; rr < 4; ++rr) {
          uint4 w4 = *(const uint4*)(wb + rr * 260 + j * 64);
          a0[rr] = dot2bf(w4.x, c4.x, a0[rr]);
          a0[rr] = dot2bf(w4.y, c4.y, a0[rr]);
          a0[rr] = dot2bf(w4.z, c4.z, a0[rr]);
          a0[rr] = dot2bf(w4.w, c4.w, a0[rr]);
          a1[rr] = dot2bf(w4.x, d4.x, a1[rr]);
          a1[rr] = dot2bf(w4.y, d4.y, a1[rr]);
          a1[rr] = dot2bf(w4.z, d4.z, a1[rr]);
          a1[rr] = dot2bf(w4.w, d4.w, a1[rr]);
        }
      }
#pragma unroll
      for (int rr = 0; rr < 4; ++rr) {
        const int row = 4 * rgrp + rr;
        part[row * 34 + kwi]      = a0[rr];
        part[row * 34 + 16 + kwi] = a1[rr];
      }
    }
    __syncthreads();

    if (tid < 128) {
      // finalize rows 2fp, 2fp+1 of batch fb2: sum 16 kwi partials each
      const float* p0 = &part[(2 * fp) * 34 + fb2 * 16];
      const float* p1 = &part[(2 * fp + 1) * 34 + fb2 * 16];
      float s0 = 0.f, s1 = 0.f;
#pragma unroll
      for (int t = 0; t < 4; ++t) {
        float4 q0 = ((const float4*)p0)[t];
        float4 q1 = ((const float4*)p1)[t];
        s0 += (q0.x + q0.y) + (q0.z + q0.w);
        s1 += (q1.x + q1.y) + (q1.z + q1.w);
      }
      float t0 = tanhf(s0 + biasv.x + bf2f(ep0 & 0xffffu));
      float t1 = tanhf(s1 + biasv.y + bf2f(ep0 >> 16));
      uint32_t pr = pk2(t0, t1);
      // write own quarter into cT (transposed position), m = qh*64+fp
      {
        const int m = qh * 64 + fp;
        cT[fb2 * 264 + ((m >> 2) & 3) * 64 + (m >> 4) * 4 + (m & 3)] = pr;
      }
      if (i != 511) {
        uint64_t pkt = ((uint64_t)(uint32_t)(i + 1) << 32) | (uint64_t)pr;
        __hip_atomic_store(&cbuf[(size_t)(((i & 1) * 256 + bid) * 128 + tid)],
                           pkt, __ATOMIC_RELAXED, __HIP_MEMORY_SCOPE_AGENT);
        prPrev = pr; sPrev = s;
      } else {
        *(uint32_t*)&cat[(size_t)(s * BB + b0 + fb2) * KCAT + fcol] = pr;
      }
    } else if (i != 511) {
      // poll-gather one partner word; seq embedded -> single round trip
      const uint64_t want = (uint64_t)(uint32_t)(i + 1);
      const uint64_t* slot = &cbuf[(size_t)(((i & 1) * 256 + pbid) * 128 + gj)];
      uint64_t v = __hip_atomic_load(slot, __ATOMIC_RELAXED, __HIP_MEMORY_SCOPE_AGENT);
      while ((v >> 32) != want) {
        __builtin_amdgcn_s_sleep(1);
        v = __hip_atomic_load(slot, __ATOMIC_RELAXED, __HIP_MEMORY_SCOPE_AGENT);
      }
      cT[gdst] = (uint32_t)v;
    }

    if (i == 511) break;
    __syncthreads();

    ep0 = ep1; ep1 = ep2;
  }
}

// ---------- K4: max-reduce partials, classifier, log_softmax ----------
__global__ __launch_bounds__(256) void final_kernel(
    const float* __restrict__ partial, const float* __restrict__ Wdoc,
    const float* __restrict__ bdoc, float* __restrict__ out)
{
  const int b = blockIdx.x, t = threadIdx.x;
  __shared__ float ym[1024];
  __shared__ float lg[32];
  float m0 = -2.f, m1 = -2.f, m2 = -2.f, m3 = -2.f;
  for (int mg = 0; mg < 256; ++mg) {
    const float* p = partial + ((size_t)mg * 64 + b) * 1024;
    m0 = fmaxf(m0, p[t]);
    m1 = fmaxf(m1, p[t + 256]);
    m2 = fmaxf(m2, p[t + 512]);
    m3 = fmaxf(m3, p[t + 768]);
  }
  ym[t] = m0; ym[t + 256] = m1; ym[t + 512] = m2; ym[t + 768] = m3;
  __syncthreads();
  if (t < NCLS) {
    const float* wr = Wdoc + (size_t)t * 1024;
    float a0 = 0.f, a1 = 0.f, a2 = 0.f, a3 = 0.f;
    for (int n = 0; n < 1024; n += 4) {
      a0 = fmaf(ym[n], wr[n], a0);
      a1 = fmaf(ym[n + 1], wr[n + 1], a1);
      a2 = fmaf(ym[n + 2], wr[n + 2], a2);
      a3 = fmaf(ym[n + 3], wr[n + 3], a3);
    }
    lg[t] = (a0 + a1) + (a2 + a3) + bdoc[t];
  }
  __syncthreads();
  if (t < NCLS) {
    float mx = -1e30f;
    for (int c = 0; c < NCLS; ++c) mx = fmaxf(mx, lg[c]);
    float ssum = 0.f;
    for (int c = 0; c < NCLS; ++c) ssum += expf(lg[c] - mx);
    out[b * NCLS + t] = lg[t] - mx - logf(ssum);
  }
}

// ---------- launch ----------
extern "C" void kernel_launch(void* const* d_in, const int* in_sizes, int n_in,
                              void* d_out, int out_size, void* d_ws, size_t ws_size,
                              hipStream_t stream) {
  const int*   inp   = (const int*)  d_in[0];
  const float* table = (const float*)d_in[1];
  const float* cl0   = (const float*)d_in[2];
  const float* cr0   = (const float*)d_in[3];
  const float* Wl    = (const float*)d_in[4];
  const float* bl    = (const float*)d_in[5];
  const float* Wr    = (const float*)d_in[6];
  const float* br    = (const float*)d_in[7];
  const float* Wsl   = (const float*)d_in[8];
  const float* bsl   = (const float*)d_in[9];
  const float* Wsr   = (const float*)d_in[10];
  const float* bsr   = (const float*)d_in[11];
  const float* Wmax  = (const float*)d_in[12];
  const float* bmax  = (const float*)d_in[13];
  const float* Wdoc  = (const float*)d_in[14];
  const float* bdoc  = (const float*)d_in[15];

  uint8_t* ws = (uint8_t*)d_ws;
  uint16_t* cat     = (uint16_t*)(ws);                 // 32768*1536*2 = 100663296
  uint16_t* ee      = (uint16_t*)(ws + 100663296);     // 32768*1024*2 = 67108864
  float*    partial = (float*)   (ws + 167772160);     // 256*64*1024*4 = 67108864
  uint16_t* wslb    = (uint16_t*)(ws + 234881024);     // 524288
  uint16_t* wsrb    = (uint16_t*)(ws + 235405312);     // 524288
  uint16_t* wmaxb   = (uint16_t*)(ws + 235929600);     // 3145728
  uint16_t* wlb     = (uint16_t*)(ws + 239075328);     // 524288
  uint16_t* wrb     = (uint16_t*)(ws + 239599616);     // 524288
  // cbuf (u64 seq|payload, 2 parity x 256 bid x 128 words = 512 KB) overlays the
  // START of `partial`: poisoned 0xAA at launch (seq never matches), and gemm<1>
  // fully overwrites partial AFTER the scan completes. No ws growth.
  uint64_t* cbuf    = (uint64_t*)(ws + 167772160);

  prep_kernel<<<9472, 256, 0, stream>>>(inp, table, Wsl, Wsr, Wl, Wr, Wmax,
                                        cat, wslb, wsrb, wlb, wrb, wmaxb);
  gemm_kernel<0><<<dim3(256, 8), 256, 0, stream>>>(cat + 512, KCAT, 512, wslb, wsrb,
                                                   bsl, bsr, ee, nullptr);
  scan_kernel<<<256, 512, 0, stream>>>(ee, wlb, wrb, bl, br, cl0, cr0, cat, cbuf);
  gemm_kernel<1><<<dim3(256, 8), 256, 0, stream>>>(cat, KCAT, KCAT, wmaxb, nullptr,
                                                   bmax, nullptr, nullptr, partial);
  final_kernel<<<64, 256, 0, stream>>>(partial, Wdoc, bdoc, (float*)d_out);
}